// Round 11
// baseline (238.564 us; speedup 1.0000x reference)
//
#include <hip/hip_runtime.h>
#include <hip/hip_fp16.h>
#include <stdint.h>

// x[16384,2048] f32, w[2048,2048] f32, bias[2048] f32, scalar scales.
// M=16384, N=2048, K=2048. Output f16 values stored as f32.
#define MDIM 16384
#define NDIM 2048
#define KDIM 2048

typedef __attribute__((ext_vector_type(4))) float f32x4;
typedef __attribute__((ext_vector_type(4))) int   i32x4;
typedef __attribute__((ext_vector_type(8))) int   i32x8;

#if defined(__has_builtin)
#if __has_builtin(__builtin_amdgcn_cvt_pk_fp8_f32)
#define HAVE_CVT_PK_FP8 1
#endif
#endif

// ---------------------------------------------------------------------------
// f32 -> e4m3fn (OCP), RTNE, saturating (== clip(+-448) then cast).
// ---------------------------------------------------------------------------
__device__ __forceinline__ unsigned f32_to_e4m3(float x) {
    float q = fminf(448.f, fmaxf(-448.f, x));
    unsigned ub = __float_as_uint(q);
    unsigned sgn = (ub >> 24) & 0x80u;
    float aq = fabsf(q);
    int E = (int)((__float_as_uint(aq) >> 23) & 0xff) - 127;
    if (E < -6) E = -6;
    float rq = __uint_as_float((unsigned)(130 - E) << 23);  // 2^(3-E), exact
    int m = (int)rintf(aq * rq);                            // RTNE, exact scale
    if (m == 16) { m = 8; E += 1; }
    unsigned bits;
    if (m < 8) bits = sgn | (unsigned)m;
    else       bits = sgn | ((unsigned)(E + 7) << 3) | (unsigned)(m - 8);
    return bits;
}

__device__ __forceinline__ uint32_t pack4_e4m3(float a, float b, float c, float d) {
#ifdef HAVE_CVT_PK_FP8
    int r = __builtin_amdgcn_cvt_pk_fp8_f32(a, b, 0, false);   // bytes 0-1
    r = __builtin_amdgcn_cvt_pk_fp8_f32(c, d, r, true);        // bytes 2-3
    return (uint32_t)r;
#else
    return f32_to_e4m3(a) | (f32_to_e4m3(b) << 8) |
           (f32_to_e4m3(c) << 16) | (f32_to_e4m3(d) << 24);
#endif
}

// x-quant: linear layout.  w-quant: fragment-major packed layout Bp (r8,
// correctness-verified): 2048B block (n16 = col>>4, kb = ktile) holds at
// lane*32 (lane = g*16 + r15) bytes w[n16*16+r15][kb*128 + g*32 .. +31].
__global__ void quant_both_kernel(const float* __restrict__ x,
                                  uint8_t* __restrict__ xq,
                                  const float* __restrict__ w,
                                  uint8_t* __restrict__ wq,
                                  const float* __restrict__ s_in,
                                  const float* __restrict__ s_w) {
    if (blockIdx.x < 2048) {
        float sc = s_in[0];
        unsigned n16 = (unsigned)((size_t)MDIM * KDIM / 16);
        unsigned i = blockIdx.x * 256 + threadIdx.x;
        for (; i < n16; i += 2048 * 256) {
            const float4* xp = (const float4*)(x + (size_t)i * 16);
            uint32_t wd[4];
#pragma unroll
            for (int j = 0; j < 4; ++j) {
                float4 v = xp[j];
                wd[j] = pack4_e4m3(v.x / sc, v.y / sc, v.z / sc, v.w / sc);
            }
            ((uint4*)xq)[i] = make_uint4(wd[0], wd[1], wd[2], wd[3]);
        }
    } else {
        float sc = s_w[0];
        unsigned n16 = (unsigned)((size_t)NDIM * KDIM / 16);
        unsigned i = (blockIdx.x - 2048) * 256 + threadIdx.x;
        for (; i < n16; i += 256 * 256) {
            const float4* xp = (const float4*)(w + (size_t)i * 16);
            uint32_t wd[4];
#pragma unroll
            for (int j = 0; j < 4; ++j) {
                float4 v = xp[j];
                wd[j] = pack4_e4m3(v.x / sc, v.y / sc, v.z / sc, v.w / sc);
            }
            unsigned r = i >> 7, kc = i & 127;
            unsigned idx = ((r >> 4) * 16 + (kc >> 3)) * 128 +
                           ((kc & 7) >> 1) * 32 + (r & 15) * 2 + (kc & 1);
            ((uint4*)wq)[idx] = make_uint4(wd[0], wd[1], wd[2], wd[3]);
        }
    }
}

// ---------------------------------------------------------------------------
// GEMM: C = Aq * Bp^T, fp8 e4m3, mfma_scale_f32_16x16x128_f8f6f4 (unit
// scales: exact, 2x fp8 rate, 32 contiguous K-bytes/lane; verified r4-r10).
//
// Round-11 structure (r5-r10: all LDS-A+LDS-B schedules pinned ~33% MfmaUtil;
// LDS port 2048cy co-critical with MFMA 2212cy per CU-tile):
//   B DIRECT global->reg from packed wq (L2-resident, 4MB): ping-pong
//   bfA/bfB, issued at tile top (intra-tile cover ~2000cy > 900cy HBM).
//   A via LDS dbuf 2x32KiB: port load now 128KiB reads + 32KiB writes
//   ~1280cy << MFMA -> LDS decisively sub-critical.
//   __launch_bounds__(512,2): 2 waves/SIMD guaranteed, 256-reg budget;
//   regs: acc 128(AGPR) + bf 64 + af rolling-pair 16 + addr ~30 (r8's spill
//   was the missing min-waves arg).
//   One __syncthreads per tile (full drain = exactly the required semantics;
//   stage target NXT freed by the barrier just passed -> race-free).
// A chunk swizzle per 128B row: phys=(c+row)&7, linear gload_lds dest,
// inverse on global src, same perm on af reads (2-way residual, r4-r10).
// Epilogue: [64][256] f32 slab (64KiB LDS), 4 passes, 1KiB dwordx4 rows.
// ---------------------------------------------------------------------------
#define BM 256
#define BN 256
#define BKB 128
#define NKT (KDIM / BKB)   // 16

__device__ __forceinline__ void gload_lds16(const uint8_t* g, uint8_t* l) {
    __builtin_amdgcn_global_load_lds(
        (const __attribute__((address_space(1))) void*)g,
        (__attribute__((address_space(3))) void*)l, 16, 0, 0);
}

__device__ __forceinline__ void barrier_raw() {
    asm volatile("" ::: "memory");
    __builtin_amdgcn_s_barrier();
    asm volatile("" ::: "memory");
}

__global__ __launch_bounds__(512, 2) void gemm_fp8_kernel(
    const uint8_t* __restrict__ Aq, const uint8_t* __restrict__ Bp,
    const float* __restrict__ bias, const float* __restrict__ s_in,
    const float* __restrict__ s_w, float* __restrict__ out) {

    extern __shared__ uint8_t lds[];   // 65536 B: 2 x 32KiB A-buf / f32[64][256]

    // XCD-aware bijective swizzle (nwg = 512, divisible by 8)
    int nwg = gridDim.x;
    int cpx = nwg >> 3;
    int bid = blockIdx.x;
    int swz = (bid & 7) * cpx + (bid >> 3);
    int tm = swz >> 3;                 // tiles_n = 8
    int tn = swz & 7;
    int row0 = tm * BM;
    int col0 = tn * BN;

    int tid  = threadIdx.x;
    int lane = tid & 63;
    int wid  = tid >> 6;
    int wr = wid >> 2, wc = wid & 3;   // 2M x 4N, per-wave 128x64
    int r15 = lane & 15;
    int g   = lane >> 4;

    int perm0 = ((2 * g + r15) & 7) << 4;
    int perm1 = ((2 * g + 1 + r15) & 7) << 4;

    // ---- A staging: 2048 chunks/tile (256 rows x 8), 4 per thread ----
    int ssrc[4], sdst[4];
#pragma unroll
    for (int i = 0; i < 4; ++i) {
        int p = i * 512 + tid;
        int lrow = p >> 3;
        int c = ((p & 7) - (lrow & 7)) & 7;
        ssrc[i] = lrow * KDIM + c * 16;
        sdst[i] = p * 16;
    }
    const uint8_t* Asrc = Aq + (size_t)row0 * KDIM;

#define STAGE_A(KT, BUF)                                                      \
    {                                                                         \
        _Pragma("unroll")                                                     \
        for (int j_ = 0; j_ < 4; ++j_)                                        \
            gload_lds16(Asrc + ssrc[j_] + (size_t)(KT) * BKB, (BUF) + sdst[j_]); \
    }

    // ---- B fragment bases (packed layout; r8-verified) ----
    const uint8_t* bfbase[4];
#pragma unroll
    for (int n = 0; n < 4; ++n) {
        int n16g = tn * 16 + wc * 4 + n;
        bfbase[n] = Bp + (size_t)n16g * 32768 + lane * 32;
    }

#define LOAD_BF_G(DST, KT)                                                    \
    {                                                                         \
        _Pragma("unroll")                                                     \
        for (int n_ = 0; n_ < 4; ++n_) {                                      \
            const uint8_t* p_ = bfbase[n_] + (size_t)(KT) * 2048;             \
            i32x4 lo = *(const i32x4*)p_;                                     \
            i32x4 hi = *(const i32x4*)(p_ + 16);                              \
            _Pragma("unroll")                                                 \
            for (int q_ = 0; q_ < 4; ++q_) { DST[n_][q_] = lo[q_]; DST[n_][4 + q_] = hi[q_]; } \
        }                                                                     \
    }

    int aRow0 = wr * 128 + r15;        // + MH*64 + m*16

#define LOAD_AF1(DST, BUF, MH, M)                                             \
    {                                                                         \
        const uint8_t* rp = (BUF) + (aRow0 + (MH) * 64 + (M) * 16) * 128;     \
        i32x4 lo = *(const i32x4*)(rp + perm0);                               \
        i32x4 hi = *(const i32x4*)(rp + perm1);                               \
        _Pragma("unroll")                                                     \
        for (int q_ = 0; q_ < 4; ++q_) { DST[q_] = lo[q_]; DST[4 + q_] = hi[q_]; } \
    }

#define MFMA_ROW(AF, MH, M, BF)                                               \
    __builtin_amdgcn_s_setprio(1);                                            \
    _Pragma("unroll")                                                         \
    for (int n_ = 0; n_ < 4; ++n_)                                            \
        acc[(MH) * 4 + (M)][n_] =                                             \
            __builtin_amdgcn_mfma_scale_f32_16x16x128_f8f6f4(                 \
                AF, BF[n_], acc[(MH) * 4 + (M)][n_], 0, 0, 0, 127, 0, 127);   \
    __builtin_amdgcn_s_setprio(0);

    // rolling-pair A fragments: 2 live i32x8 (16 VGPR)
#define MH_BLOCK(BUF, MH, BF)                                                 \
    {                                                                         \
        i32x8 afe, afo;                                                       \
        LOAD_AF1(afe, BUF, MH, 0);                                            \
        LOAD_AF1(afo, BUF, MH, 1); MFMA_ROW(afe, MH, 0, BF);                  \
        LOAD_AF1(afe, BUF, MH, 2); MFMA_ROW(afo, MH, 1, BF);                  \
        LOAD_AF1(afo, BUF, MH, 3); MFMA_ROW(afe, MH, 2, BF);                  \
                                   MFMA_ROW(afo, MH, 3, BF);                  \
    }

#define TILE_BODY(T, BFC, BFN)                                                \
    {                                                                         \
        uint8_t* cur_ = ((T) & 1) ? buf1 : buf0;                              \
        uint8_t* nxt_ = ((T) & 1) ? buf0 : buf1;                              \
        if ((T) + 1 < NKT) {                                                  \
            STAGE_A((T) + 1, nxt_);                                           \
            LOAD_BF_G(BFN, (T) + 1);                                          \
        }                                                                     \
        MH_BLOCK(cur_, 0, BFC);                                               \
        MH_BLOCK(cur_, 1, BFC);                                               \
        __syncthreads();                                                      \
    }

    f32x4 acc[8][4];
#pragma unroll
    for (int m = 0; m < 8; ++m)
#pragma unroll
        for (int n = 0; n < 4; ++n)
            acc[m][n] = (f32x4){0.f, 0.f, 0.f, 0.f};

    i32x8 bfA[4], bfB[4];
    uint8_t* buf0 = &lds[0];
    uint8_t* buf1 = &lds[32768];

    // ---- prologue: A(0), bf(0), full drain ----
    STAGE_A(0, buf0);
    LOAD_BF_G(bfA, 0);
    __syncthreads();

    for (int t = 0; t < NKT; t += 2) {
        TILE_BODY(t, bfA, bfB);
        TILE_BODY(t + 1, bfB, bfA);
    }

    // ---- epilogue: f16 double-round + bias; [64][256] f32 slab, 4 passes --
    float s = s_in[0] * s_w[0];
    float* slab = (float*)lds;
    __half hb[4];
#pragma unroll
    for (int n = 0; n < 4; ++n)
        hb[n] = __float2half(bias[col0 + wc * 64 + n * 16 + r15]);

#pragma unroll
    for (int q = 0; q < 4; ++q) {            // out rows [q*64, q*64+64)
        if (wr == (q >> 1)) {
            const int mh = q & 1;
#pragma unroll
            for (int n = 0; n < 4; ++n) {
                int colb = wc * 64 + n * 16 + r15;
#pragma unroll
                for (int m = 0; m < 4; ++m) {
                    int sr = m * 16 + g * 4;
#pragma unroll
                    for (int r = 0; r < 4; ++r) {
                        __half h = __float2half(acc[mh * 4 + m][n][r] * s);
                        slab[(sr + r) * 256 + colb] = __half2float(__hadd(h, hb[n]));
                    }
                }
            }
        }
        barrier_raw();
#pragma unroll
        for (int it = 0; it < 8; ++it) {
            int srow = wid * 8 + it;
            f32x4 vv = *(const f32x4*)&slab[srow * 256 + lane * 4];
            int grow = row0 + q * 64 + srow;
            *(f32x4*)&out[(size_t)grow * NDIM + col0 + lane * 4] = vv;
        }
        barrier_raw();
    }
#undef STAGE_A
#undef LOAD_BF_G
#undef LOAD_AF1
#undef MFMA_ROW
#undef MH_BLOCK
#undef TILE_BODY
}

// ---------------------------------------------------------------------------
extern "C" void kernel_launch(void* const* d_in, const int* in_sizes, int n_in,
                              void* d_out, int out_size, void* d_ws, size_t ws_size,
                              hipStream_t stream) {
    const float* x      = (const float*)d_in[0];   // [16384, 2048]
    const float* weight = (const float*)d_in[1];   // [2048, 2048]
    const float* bias   = (const float*)d_in[2];   // [2048]
    const float* s_in   = (const float*)d_in[3];   // [1]
    const float* s_w    = (const float*)d_in[4];   // [1]
    float* out          = (float*)d_out;

    uint8_t* xq = (uint8_t*)d_ws;                          // 33.5 MB (linear)
    uint8_t* wq = (uint8_t*)d_ws + (size_t)MDIM * KDIM;    // 4.2 MB (packed)

    quant_both_kernel<<<2304, 256, 0, stream>>>(x, xq, weight, wq, s_in, s_w);

    dim3 grid((MDIM / BM) * (NDIM / BN));   // 64 * 8 = 512
    gemm_fp8_kernel<<<grid, 512, 65536, stream>>>(xq, wq, bias, s_in, s_w, out);
}

// Round 12
// 121.263 us; speedup vs baseline: 1.9673x; 1.9673x over previous
//
#include <hip/hip_runtime.h>
#include <hip/hip_fp16.h>
#include <stdint.h>

// x[16384,2048] f32, w[2048,2048] f32, bias[2048] f32, scalar scales.
// M=16384, N=2048, K=2048. Output f16 values stored as f32.
#define MDIM 16384
#define NDIM 2048
#define KDIM 2048

typedef __attribute__((ext_vector_type(4))) float f32x4;
typedef __attribute__((ext_vector_type(4))) int   i32x4;
typedef __attribute__((ext_vector_type(8))) int   i32x8;

#if defined(__has_builtin)
#if __has_builtin(__builtin_amdgcn_cvt_pk_fp8_f32)
#define HAVE_CVT_PK_FP8 1
#endif
#endif

// ---------------------------------------------------------------------------
// f32 -> e4m3fn (OCP), RTNE, saturating (== clip(+-448) then cast).
// ---------------------------------------------------------------------------
__device__ __forceinline__ unsigned f32_to_e4m3(float x) {
    float q = fminf(448.f, fmaxf(-448.f, x));
    unsigned ub = __float_as_uint(q);
    unsigned sgn = (ub >> 24) & 0x80u;
    float aq = fabsf(q);
    int E = (int)((__float_as_uint(aq) >> 23) & 0xff) - 127;
    if (E < -6) E = -6;
    float rq = __uint_as_float((unsigned)(130 - E) << 23);  // 2^(3-E), exact
    int m = (int)rintf(aq * rq);                            // RTNE, exact scale
    if (m == 16) { m = 8; E += 1; }
    unsigned bits;
    if (m < 8) bits = sgn | (unsigned)m;
    else       bits = sgn | ((unsigned)(E + 7) << 3) | (unsigned)(m - 8);
    return bits;
}

__device__ __forceinline__ uint32_t pack4_e4m3(float a, float b, float c, float d) {
#ifdef HAVE_CVT_PK_FP8
    int r = __builtin_amdgcn_cvt_pk_fp8_f32(a, b, 0, false);   // bytes 0-1
    r = __builtin_amdgcn_cvt_pk_fp8_f32(c, d, r, true);        // bytes 2-3
    return (uint32_t)r;
#else
    return f32_to_e4m3(a) | (f32_to_e4m3(b) << 8) |
           (f32_to_e4m3(c) << 16) | (f32_to_e4m3(d) << 24);
#endif
}

// x-quant: linear layout.  w-quant: fragment-major packed layout Bp
// (verified r8/r11): 2048B block (n16 = col>>4, kb = ktile) holds at
// lane*32 (lane = g*16 + r15) bytes w[n16*16+r15][kb*128 + g*32 .. +31].
__global__ void quant_both_kernel(const float* __restrict__ x,
                                  uint8_t* __restrict__ xq,
                                  const float* __restrict__ w,
                                  uint8_t* __restrict__ wq,
                                  const float* __restrict__ s_in,
                                  const float* __restrict__ s_w) {
    if (blockIdx.x < 2048) {
        float sc = s_in[0];
        unsigned n16 = (unsigned)((size_t)MDIM * KDIM / 16);
        unsigned i = blockIdx.x * 256 + threadIdx.x;
        for (; i < n16; i += 2048 * 256) {
            const float4* xp = (const float4*)(x + (size_t)i * 16);
            uint32_t wd[4];
#pragma unroll
            for (int j = 0; j < 4; ++j) {
                float4 v = xp[j];
                wd[j] = pack4_e4m3(v.x / sc, v.y / sc, v.z / sc, v.w / sc);
            }
            ((uint4*)xq)[i] = make_uint4(wd[0], wd[1], wd[2], wd[3]);
        }
    } else {
        float sc = s_w[0];
        unsigned n16 = (unsigned)((size_t)NDIM * KDIM / 16);
        unsigned i = (blockIdx.x - 2048) * 256 + threadIdx.x;
        for (; i < n16; i += 256 * 256) {
            const float4* xp = (const float4*)(w + (size_t)i * 16);
            uint32_t wd[4];
#pragma unroll
            for (int j = 0; j < 4; ++j) {
                float4 v = xp[j];
                wd[j] = pack4_e4m3(v.x / sc, v.y / sc, v.z / sc, v.w / sc);
            }
            unsigned r = i >> 7, kc = i & 127;
            unsigned idx = ((r >> 4) * 16 + (kc >> 3)) * 128 +
                           ((kc & 7) >> 1) * 32 + (r & 15) * 2 + (kc & 1);
            ((uint4*)wq)[idx] = make_uint4(wd[0], wd[1], wd[2], wd[3]);
        }
    }
}

// ---------------------------------------------------------------------------
// GEMM: C = Aq * Bp^T, fp8 e4m3, mfma_scale_f32_16x16x128_f8f6f4 (unit
// scales: exact, 2x fp8 rate; verified r4-r11).
//
// Round-12: B-direct-from-L2, SINGLE bf set (the only reg-feasible variant:
// acc 128(AGPR) + bf 32 + af rolling 16 + addr ~35 = ~211 <= 256 unified
// 2-wave budget; r8/r11 spilled at ~244 with doubled fragments).
// 256x256 tile, 8 waves 2Mx4N (per-wave 128x64), BKB=128, NKT=16.
// A via LDS dbuf 2x32KiB: LDS port/tile = 128 af reads + DMA writes
// ~1790cy < MFMA 2208cy.  B frags 2KB dense per (wave,n) from packed wq
// (L2-resident 4MB): per CU-tile L2 supply ~96KB ~1714cy < 2208.
//
// Per tile: {load bf0-3 (8 dwordx4); fence; stage A(t+1) DMA (4, issued
// AFTER bf so FIFO drains bf first - compiler inserts counted vmcnt for bf);
// 8x[af-rolling ds_read pair + 4 MFMA (m-outer, n-inner, bf all live)];
// vmcnt(0) (A(t+1) landed, issued ~2400cy earlier -> no stall); barrier}.
// Accepted cost: ~300cy L2 latency at tile start for bf (no reg room to
// prefetch across tiles without spilling).
//
// A chunk swizzle per 128B row: phys=(c+row)&7, linear gload_lds dest,
// inverse on global src, same perm on af reads (2-way residual, r4-r11).
// Epilogue: [64][256] f32 slab (64KiB LDS), 4 passes, 1KiB dwordx4 rows.
// ---------------------------------------------------------------------------
#define BM 256
#define BN 256
#define BKB 128
#define NKT (KDIM / BKB)   // 16

__device__ __forceinline__ void gload_lds16(const uint8_t* g, uint8_t* l) {
    __builtin_amdgcn_global_load_lds(
        (const __attribute__((address_space(1))) void*)g,
        (__attribute__((address_space(3))) void*)l, 16, 0, 0);
}

__device__ __forceinline__ void barrier_raw() {
    asm volatile("" ::: "memory");
    __builtin_amdgcn_s_barrier();
    asm volatile("" ::: "memory");
}

__global__ __launch_bounds__(512, 2) void gemm_fp8_kernel(
    const uint8_t* __restrict__ Aq, const uint8_t* __restrict__ Bp,
    const float* __restrict__ bias, const float* __restrict__ s_in,
    const float* __restrict__ s_w, float* __restrict__ out) {

    extern __shared__ uint8_t lds[];   // 65536 B: 2 x 32KiB A-buf / f32[64][256]

    // XCD-aware bijective swizzle (nwg = 512, divisible by 8)
    int nwg = gridDim.x;
    int cpx = nwg >> 3;
    int bid = blockIdx.x;
    int swz = (bid & 7) * cpx + (bid >> 3);
    int tm = swz >> 3;                 // tiles_n = 8
    int tn = swz & 7;
    int row0 = tm * BM;
    int col0 = tn * BN;

    int tid  = threadIdx.x;
    int lane = tid & 63;
    int wid  = tid >> 6;
    int wr = wid >> 2, wc = wid & 3;   // 2M x 4N, per-wave 128x64
    int r15 = lane & 15;
    int g   = lane >> 4;

    int perm0 = ((2 * g + r15) & 7) << 4;
    int perm1 = ((2 * g + 1 + r15) & 7) << 4;

    // ---- A staging: 2048 chunks/tile (256 rows x 8), 4 per thread ----
    int ssrc[4], sdst[4];
#pragma unroll
    for (int i = 0; i < 4; ++i) {
        int p = i * 512 + tid;
        int lrow = p >> 3;
        int c = ((p & 7) - (lrow & 7)) & 7;
        ssrc[i] = lrow * KDIM + c * 16;
        sdst[i] = p * 16;
    }
    const uint8_t* Asrc = Aq + (size_t)row0 * KDIM;

#define STAGE_A(KT, BUF)                                                      \
    {                                                                         \
        _Pragma("unroll")                                                     \
        for (int j_ = 0; j_ < 4; ++j_)                                        \
            gload_lds16(Asrc + ssrc[j_] + (size_t)(KT) * BKB, (BUF) + sdst[j_]); \
    }

    // ---- B fragment bases (packed layout; r8/r11-verified) ----
    const uint8_t* bfbase[4];
#pragma unroll
    for (int n = 0; n < 4; ++n) {
        int n16g = tn * 16 + wc * 4 + n;
        bfbase[n] = Bp + (size_t)n16g * 32768 + lane * 32;
    }

#define LOAD_BF1(DST, N, KT)                                                  \
    {                                                                         \
        const uint8_t* p_ = bfbase[N] + (size_t)(KT) * 2048;                  \
        i32x4 lo = *(const i32x4*)p_;                                         \
        i32x4 hi = *(const i32x4*)(p_ + 16);                                  \
        _Pragma("unroll")                                                     \
        for (int q_ = 0; q_ < 4; ++q_) { DST[q_] = lo[q_]; DST[4 + q_] = hi[q_]; } \
    }

    int aRow0 = wr * 128 + r15;        // + m*16

#define LOAD_AF1(DST, bo, M)                                                  \
    {                                                                         \
        const uint8_t* rp = lds + (bo) + (aRow0 + (M) * 16) * 128;            \
        i32x4 lo = *(const i32x4*)(rp + perm0);                               \
        i32x4 hi = *(const i32x4*)(rp + perm1);                               \
        _Pragma("unroll")                                                     \
        for (int q_ = 0; q_ < 4; ++q_) { DST[q_] = lo[q_]; DST[4 + q_] = hi[q_]; } \
    }

#define MFMA4(AF, M)                                                          \
    __builtin_amdgcn_s_setprio(1);                                            \
    acc[M][0] = __builtin_amdgcn_mfma_scale_f32_16x16x128_f8f6f4(             \
        AF, bf0, acc[M][0], 0, 0, 0, 127, 0, 127);                            \
    acc[M][1] = __builtin_amdgcn_mfma_scale_f32_16x16x128_f8f6f4(             \
        AF, bf1, acc[M][1], 0, 0, 0, 127, 0, 127);                            \
    acc[M][2] = __builtin_amdgcn_mfma_scale_f32_16x16x128_f8f6f4(             \
        AF, bf2, acc[M][2], 0, 0, 0, 127, 0, 127);                            \
    acc[M][3] = __builtin_amdgcn_mfma_scale_f32_16x16x128_f8f6f4(             \
        AF, bf3, acc[M][3], 0, 0, 0, 127, 0, 127);                            \
    __builtin_amdgcn_s_setprio(0);

    f32x4 acc[8][4];
#pragma unroll
    for (int m = 0; m < 8; ++m)
#pragma unroll
        for (int n = 0; n < 4; ++n)
            acc[m][n] = (f32x4){0.f, 0.f, 0.f, 0.f};

    i32x8 bf0, bf1, bf2, bf3;

    uint8_t* buf0 = &lds[0];
    uint8_t* buf1 = &lds[32768];

    // ---- prologue: stage A(0), drain, barrier ----
    STAGE_A(0, buf0);
    asm volatile("s_waitcnt vmcnt(0)" ::: "memory");
    barrier_raw();

#define TILE_BODY(T)                                                          \
    {                                                                         \
        const unsigned bo = ((unsigned)(T) & 1) << 15;                        \
        uint8_t* nxt_ = (((T) & 1) ? buf0 : buf1);                            \
        LOAD_BF1(bf0, 0, T); LOAD_BF1(bf1, 1, T);                             \
        LOAD_BF1(bf2, 2, T); LOAD_BF1(bf3, 3, T);                             \
        asm volatile("" ::: "memory");   /* keep DMA after bf loads (FIFO) */ \
        if ((T) + 1 < NKT) STAGE_A((T) + 1, nxt_);                            \
        i32x8 afE, afO;                                                       \
        LOAD_AF1(afE, bo, 0);                                                 \
        LOAD_AF1(afO, bo, 1); MFMA4(afE, 0);                                  \
        LOAD_AF1(afE, bo, 2); MFMA4(afO, 1);                                  \
        LOAD_AF1(afO, bo, 3); MFMA4(afE, 2);                                  \
        LOAD_AF1(afE, bo, 4); MFMA4(afO, 3);                                  \
        LOAD_AF1(afO, bo, 5); MFMA4(afE, 4);                                  \
        LOAD_AF1(afE, bo, 6); MFMA4(afO, 5);                                  \
        LOAD_AF1(afO, bo, 7); MFMA4(afE, 6);                                  \
                              MFMA4(afO, 7);                                  \
        asm volatile("s_waitcnt vmcnt(0)" ::: "memory"); /* A(T+1) landed */  \
        barrier_raw();                                                        \
    }

    for (int t = 0; t < NKT; ++t)
        TILE_BODY(t);

    // ---- epilogue: f16 double-round + bias; [64][256] f32 slab, 4 passes --
    float s = s_in[0] * s_w[0];
    float* slab = (float*)lds;
    __half hb[4];
#pragma unroll
    for (int n = 0; n < 4; ++n)
        hb[n] = __float2half(bias[col0 + wc * 64 + n * 16 + r15]);

#pragma unroll
    for (int q = 0; q < 4; ++q) {            // out rows [q*64, q*64+64)
        if (wr == (q >> 1)) {
            const int mh = q & 1;
#pragma unroll
            for (int n = 0; n < 4; ++n) {
                int colb = wc * 64 + n * 16 + r15;
#pragma unroll
                for (int m = 0; m < 4; ++m) {
                    int sr = m * 16 + g * 4;
#pragma unroll
                    for (int r = 0; r < 4; ++r) {
                        __half h = __float2half(acc[mh * 4 + m][n][r] * s);
                        slab[(sr + r) * 256 + colb] = __half2float(__hadd(h, hb[n]));
                    }
                }
            }
        }
        barrier_raw();
#pragma unroll
        for (int it = 0; it < 8; ++it) {
            int srow = wid * 8 + it;
            f32x4 vv = *(const f32x4*)&slab[srow * 256 + lane * 4];
            int grow = row0 + q * 64 + srow;
            *(f32x4*)&out[(size_t)grow * NDIM + col0 + lane * 4] = vv;
        }
        barrier_raw();
    }
#undef STAGE_A
#undef LOAD_BF1
#undef LOAD_AF1
#undef MFMA4
#undef TILE_BODY
}

// ---------------------------------------------------------------------------
extern "C" void kernel_launch(void* const* d_in, const int* in_sizes, int n_in,
                              void* d_out, int out_size, void* d_ws, size_t ws_size,
                              hipStream_t stream) {
    const float* x      = (const float*)d_in[0];   // [16384, 2048]
    const float* weight = (const float*)d_in[1];   // [2048, 2048]
    const float* bias   = (const float*)d_in[2];   // [2048]
    const float* s_in   = (const float*)d_in[3];   // [1]
    const float* s_w    = (const float*)d_in[4];   // [1]
    float* out          = (float*)d_out;

    uint8_t* xq = (uint8_t*)d_ws;                          // 33.5 MB (linear)
    uint8_t* wq = (uint8_t*)d_ws + (size_t)MDIM * KDIM;    // 4.2 MB (packed)

    quant_both_kernel<<<2304, 256, 0, stream>>>(x, xq, weight, wq, s_in, s_w);

    dim3 grid((MDIM / BM) * (NDIM / BN));   // 64 * 8 = 512
    gemm_fp8_kernel<<<grid, 512, 65536, stream>>>(xq, wq, bias, s_in, s_w, out);
}

// Round 13
// 112.006 us; speedup vs baseline: 2.1299x; 1.0826x over previous
//
#include <hip/hip_runtime.h>
#include <hip/hip_fp16.h>
#include <stdint.h>

// x[16384,2048] f32, w[2048,2048] f32, bias[2048] f32, scalar scales.
// M=16384, N=2048, K=2048. Output f16 values stored as f32.
#define MDIM 16384
#define NDIM 2048
#define KDIM 2048

typedef __attribute__((ext_vector_type(4))) float f32x4;
typedef __attribute__((ext_vector_type(4))) int   i32x4;
typedef __attribute__((ext_vector_type(8))) int   i32x8;

#if defined(__has_builtin)
#if __has_builtin(__builtin_amdgcn_cvt_pk_fp8_f32)
#define HAVE_CVT_PK_FP8 1
#endif
#endif

// ---------------------------------------------------------------------------
// f32 -> e4m3fn (OCP), RTNE, saturating (== clip(+-448) then cast).
// ---------------------------------------------------------------------------
__device__ __forceinline__ unsigned f32_to_e4m3(float x) {
    float q = fminf(448.f, fmaxf(-448.f, x));
    unsigned ub = __float_as_uint(q);
    unsigned sgn = (ub >> 24) & 0x80u;
    float aq = fabsf(q);
    int E = (int)((__float_as_uint(aq) >> 23) & 0xff) - 127;
    if (E < -6) E = -6;
    float rq = __uint_as_float((unsigned)(130 - E) << 23);  // 2^(3-E), exact
    int m = (int)rintf(aq * rq);                            // RTNE, exact scale
    if (m == 16) { m = 8; E += 1; }
    unsigned bits;
    if (m < 8) bits = sgn | (unsigned)m;
    else       bits = sgn | ((unsigned)(E + 7) << 3) | (unsigned)(m - 8);
    return bits;
}

__device__ __forceinline__ uint32_t pack4_e4m3(float a, float b, float c, float d) {
#ifdef HAVE_CVT_PK_FP8
    int r = __builtin_amdgcn_cvt_pk_fp8_f32(a, b, 0, false);   // bytes 0-1
    r = __builtin_amdgcn_cvt_pk_fp8_f32(c, d, r, true);        // bytes 2-3
    return (uint32_t)r;
#else
    return f32_to_e4m3(a) | (f32_to_e4m3(b) << 8) |
           (f32_to_e4m3(c) << 16) | (f32_to_e4m3(d) << 24);
#endif
}

// x-quant: linear layout.  w-quant: fragment-major packed layout Bp
// (verified r8/r11/r12): 2048B block (n16 = col>>4, kb = ktile) holds at
// lane*32 (lane = g*16 + r15) bytes w[n16*16+r15][kb*128 + g*32 .. +31].
__global__ void quant_both_kernel(const float* __restrict__ x,
                                  uint8_t* __restrict__ xq,
                                  const float* __restrict__ w,
                                  uint8_t* __restrict__ wq,
                                  const float* __restrict__ s_in,
                                  const float* __restrict__ s_w) {
    if (blockIdx.x < 2048) {
        float sc = s_in[0];
        unsigned n16 = (unsigned)((size_t)MDIM * KDIM / 16);
        unsigned i = blockIdx.x * 256 + threadIdx.x;
        for (; i < n16; i += 2048 * 256) {
            const float4* xp = (const float4*)(x + (size_t)i * 16);
            uint32_t wd[4];
#pragma unroll
            for (int j = 0; j < 4; ++j) {
                float4 v = xp[j];
                wd[j] = pack4_e4m3(v.x / sc, v.y / sc, v.z / sc, v.w / sc);
            }
            ((uint4*)xq)[i] = make_uint4(wd[0], wd[1], wd[2], wd[3]);
        }
    } else {
        float sc = s_w[0];
        unsigned n16 = (unsigned)((size_t)NDIM * KDIM / 16);
        unsigned i = (blockIdx.x - 2048) * 256 + threadIdx.x;
        for (; i < n16; i += 256 * 256) {
            const float4* xp = (const float4*)(w + (size_t)i * 16);
            uint32_t wd[4];
#pragma unroll
            for (int j = 0; j < 4; ++j) {
                float4 v = xp[j];
                wd[j] = pack4_e4m3(v.x / sc, v.y / sc, v.z / sc, v.w / sc);
            }
            unsigned r = i >> 7, kc = i & 127;
            unsigned idx = ((r >> 4) * 16 + (kc >> 3)) * 128 +
                           ((kc & 7) >> 1) * 32 + (r & 15) * 2 + (kc & 1);
            ((uint4*)wq)[idx] = make_uint4(wd[0], wd[1], wd[2], wd[3]);
        }
    }
}

// ---------------------------------------------------------------------------
// GEMM: C = Aq * Bp^T, fp8 e4m3, mfma_scale_f32_16x16x128_f8f6f4 (unit
// scales: exact, 2x fp8 rate; verified r4-r12).
//
// Round-13: TWO independent 256-thread blocks per CU (r4-r12: one 8-wave
// barrier-locked block pins MfmaUtil at ~33% across six structures; with a
// single resident block every bf-latency/drain/barrier stall idles the whole
// CU - m114 cross-block overlap requires >=2 blocks).
//   Block: 4 waves 2Mx2N, per-wave 128x64 (proven reg shape: acc 128 AGPR +
//   bf 32 + af rolling 16 + addr ~40 -> launch_bounds(256,2), 2 blocks/CU).
//   Tile 256x128; A via LDS dbuf 2x32KiB (2 blocks = 128KiB <= 160).
//   B DIRECT from packed wq (r12), single bf set, with bf(t+1) issued
//   BEFORE the tile-end barrier (bf regs' last use = final MFMA; zero reg
//   cost): vmcnt(8) drains stage A(t+1) only, bf crosses the barrier in
//   flight -> L2 latency hidden under drain+barrier+next stage issue.
// Per tile: {stage A(t+1) 8 DMA; af-rolling 8x[2 ds_read + MFMA4];
//            issue bf(t+1) 8 loads; vmcnt(8); barrier}.
// A chunk swizzle per 128B row: phys=(c+row)&7, linear gload_lds dest,
// inverse on global src, same perm on af reads (2-way residual, r4-r12).
// Epilogue: [64][128] f32 slab (32KiB), 4 passes, 512B dwordx4 row stores.
// ---------------------------------------------------------------------------
#define BM 256
#define BN 128
#define BKB 128
#define NKT (KDIM / BKB)   // 16

__device__ __forceinline__ void gload_lds16(const uint8_t* g, uint8_t* l) {
    __builtin_amdgcn_global_load_lds(
        (const __attribute__((address_space(1))) void*)g,
        (__attribute__((address_space(3))) void*)l, 16, 0, 0);
}

__device__ __forceinline__ void barrier_raw() {
    asm volatile("" ::: "memory");
    __builtin_amdgcn_s_barrier();
    asm volatile("" ::: "memory");
}

__global__ __launch_bounds__(256, 2) void gemm_fp8_kernel(
    const uint8_t* __restrict__ Aq, const uint8_t* __restrict__ Bp,
    const float* __restrict__ bias, const float* __restrict__ s_in,
    const float* __restrict__ s_w, float* __restrict__ out) {

    extern __shared__ uint8_t lds[];   // 65536 B: 2 x 32KiB A-buf

    // XCD-aware bijective swizzle (nwg = 1024, divisible by 8)
    int nwg = gridDim.x;
    int cpx = nwg >> 3;
    int bid = blockIdx.x;
    int swz = (bid & 7) * cpx + (bid >> 3);
    int tm = swz >> 4;                 // tiles_n = 16
    int tn = swz & 15;
    int row0 = tm * BM;
    int col0 = tn * BN;

    int tid  = threadIdx.x;
    int lane = tid & 63;
    int wid  = tid >> 6;               // 4 waves
    int wr = wid >> 1, wc = wid & 1;   // 2M x 2N, per-wave 128x64
    int r15 = lane & 15;
    int g   = lane >> 4;

    int perm0 = ((2 * g + r15) & 7) << 4;
    int perm1 = ((2 * g + 1 + r15) & 7) << 4;

    // ---- A staging: 2048 chunks/tile (256 rows x 8), 8 per thread ----
    int ssrc[8], sdst[8];
#pragma unroll
    for (int i = 0; i < 8; ++i) {
        int p = i * 256 + tid;
        int lrow = p >> 3;
        int c = ((p & 7) - (lrow & 7)) & 7;
        ssrc[i] = lrow * KDIM + c * 16;
        sdst[i] = p * 16;
    }
    const uint8_t* Asrc = Aq + (size_t)row0 * KDIM;

#define STAGE_A(KT, BUF)                                                      \
    {                                                                         \
        _Pragma("unroll")                                                     \
        for (int j_ = 0; j_ < 8; ++j_)                                        \
            gload_lds16(Asrc + ssrc[j_] + (size_t)(KT) * BKB, (BUF) + sdst[j_]); \
    }

    // ---- B fragment bases (packed layout; r8/r11/r12-verified) ----
    const uint8_t* bfbase[4];
#pragma unroll
    for (int n = 0; n < 4; ++n) {
        int n16g = tn * 8 + wc * 4 + n;
        bfbase[n] = Bp + (size_t)n16g * 32768 + lane * 32;
    }

#define LOAD_BF_ALL(KT)                                                       \
    {                                                                         \
        _Pragma("unroll")                                                     \
        for (int n_ = 0; n_ < 4; ++n_) {                                      \
            const uint8_t* p_ = bfbase[n_] + (size_t)(KT) * 2048;             \
            i32x4 lo = *(const i32x4*)p_;                                     \
            i32x4 hi = *(const i32x4*)(p_ + 16);                              \
            i32x8 v_;                                                         \
            _Pragma("unroll")                                                 \
            for (int q_ = 0; q_ < 4; ++q_) { v_[q_] = lo[q_]; v_[4 + q_] = hi[q_]; } \
            if (n_ == 0) bf0 = v_; else if (n_ == 1) bf1 = v_;                \
            else if (n_ == 2) bf2 = v_; else bf3 = v_;                        \
        }                                                                     \
    }

    int aRow0 = wr * 128 + r15;        // + m*16

#define LOAD_AF1(DST, bo, M)                                                  \
    {                                                                         \
        const uint8_t* rp = lds + (bo) + (aRow0 + (M) * 16) * 128;            \
        i32x4 lo = *(const i32x4*)(rp + perm0);                               \
        i32x4 hi = *(const i32x4*)(rp + perm1);                               \
        _Pragma("unroll")                                                     \
        for (int q_ = 0; q_ < 4; ++q_) { DST[q_] = lo[q_]; DST[4 + q_] = hi[q_]; } \
    }

#define MFMA4(AF, M)                                                          \
    __builtin_amdgcn_s_setprio(1);                                            \
    acc[M][0] = __builtin_amdgcn_mfma_scale_f32_16x16x128_f8f6f4(             \
        AF, bf0, acc[M][0], 0, 0, 0, 127, 0, 127);                            \
    acc[M][1] = __builtin_amdgcn_mfma_scale_f32_16x16x128_f8f6f4(             \
        AF, bf1, acc[M][1], 0, 0, 0, 127, 0, 127);                            \
    acc[M][2] = __builtin_amdgcn_mfma_scale_f32_16x16x128_f8f6f4(             \
        AF, bf2, acc[M][2], 0, 0, 0, 127, 0, 127);                            \
    acc[M][3] = __builtin_amdgcn_mfma_scale_f32_16x16x128_f8f6f4(             \
        AF, bf3, acc[M][3], 0, 0, 0, 127, 0, 127);                            \
    __builtin_amdgcn_s_setprio(0);

    f32x4 acc[8][4];
#pragma unroll
    for (int m = 0; m < 8; ++m)
#pragma unroll
        for (int n = 0; n < 4; ++n)
            acc[m][n] = (f32x4){0.f, 0.f, 0.f, 0.f};

    i32x8 bf0, bf1, bf2, bf3;

    uint8_t* buf0 = &lds[0];
    uint8_t* buf1 = &lds[32768];

    // ---- prologue: stage A(0) [8 DMA], bf(0) [8 loads];
    //      vmcnt(8) drains A(0), leaves bf(0) in flight; barrier ----
    STAGE_A(0, buf0);
    asm volatile("" ::: "memory");
    LOAD_BF_ALL(0);
    asm volatile("s_waitcnt vmcnt(8)" ::: "memory");
    barrier_raw();

    // Entry invariant for tile T: bf(T) in flight (8 oldest), A(T) landed.
#define TILE_BODY(T)                                                          \
    {                                                                         \
        const unsigned bo = ((unsigned)(T) & 1) << 15;                        \
        uint8_t* nxt_ = (((T) & 1) ? buf0 : buf1);                            \
        if ((T) + 1 < NKT) STAGE_A((T) + 1, nxt_);  /* 8 DMA after bf(T) */   \
        i32x8 afE, afO;                                                       \
        LOAD_AF1(afE, bo, 0);     /* compiler waits bf(T) w/ counted vmcnt */ \
        LOAD_AF1(afO, bo, 1); MFMA4(afE, 0);                                  \
        LOAD_AF1(afE, bo, 2); MFMA4(afO, 1);                                  \
        LOAD_AF1(afO, bo, 3); MFMA4(afE, 2);                                  \
        LOAD_AF1(afE, bo, 4); MFMA4(afO, 3);                                  \
        LOAD_AF1(afO, bo, 5); MFMA4(afE, 4);                                  \
        LOAD_AF1(afE, bo, 6); MFMA4(afO, 5);                                  \
        LOAD_AF1(afO, bo, 7); MFMA4(afE, 6);                                  \
                              MFMA4(afO, 7);                                  \
        if ((T) + 1 < NKT) {                                                  \
            asm volatile("" ::: "memory");                                    \
            LOAD_BF_ALL((T) + 1);          /* 8 loads, reuse bf regs */       \
            asm volatile("s_waitcnt vmcnt(8)" ::: "memory"); /* A(T+1) in */  \
        } else {                                                              \
            asm volatile("s_waitcnt vmcnt(0)" ::: "memory");                  \
        }                                                                     \
        barrier_raw();                                                        \
    }

    for (int t = 0; t < NKT; ++t)
        TILE_BODY(t);

    // ---- epilogue: f16 double-round + bias; [64][128] f32 slab, 4 passes --
    float s = s_in[0] * s_w[0];
    float* slab = (float*)lds;
    __half hb[4];
#pragma unroll
    for (int n = 0; n < 4; ++n)
        hb[n] = __float2half(bias[col0 + wc * 64 + n * 16 + r15]);

#pragma unroll
    for (int q = 0; q < 4; ++q) {            // out rows [q*64, q*64+64)
        if (wr == (q >> 1)) {
            const int mh = q & 1;
#pragma unroll
            for (int n = 0; n < 4; ++n) {
                int colb = wc * 64 + n * 16 + r15;
#pragma unroll
                for (int m = 0; m < 4; ++m) {
                    int sr = m * 16 + g * 4;
#pragma unroll
                    for (int r = 0; r < 4; ++r) {
                        __half h = __float2half(acc[mh * 4 + m][n][r] * s);
                        slab[(sr + r) * 128 + colb] = __half2float(__hadd(h, hb[n]));
                    }
                }
            }
        }
        barrier_raw();
        // 64 rows x 512B; each wave 16 rows, 2 rows/iter (32 lanes x 16B)
#pragma unroll
        for (int it = 0; it < 8; ++it) {
            int srow = wid * 16 + it * 2 + (lane >> 5);
            f32x4 vv = *(const f32x4*)&slab[srow * 128 + (lane & 31) * 4];
            int grow = row0 + q * 64 + srow;
            *(f32x4*)&out[(size_t)grow * NDIM + col0 + (lane & 31) * 4] = vv;
        }
        barrier_raw();
    }
#undef STAGE_A
#undef LOAD_BF_ALL
#undef LOAD_AF1
#undef MFMA4
#undef TILE_BODY
}

// ---------------------------------------------------------------------------
extern "C" void kernel_launch(void* const* d_in, const int* in_sizes, int n_in,
                              void* d_out, int out_size, void* d_ws, size_t ws_size,
                              hipStream_t stream) {
    const float* x      = (const float*)d_in[0];   // [16384, 2048]
    const float* weight = (const float*)d_in[1];   // [2048, 2048]
    const float* bias   = (const float*)d_in[2];   // [2048]
    const float* s_in   = (const float*)d_in[3];   // [1]
    const float* s_w    = (const float*)d_in[4];   // [1]
    float* out          = (float*)d_out;

    uint8_t* xq = (uint8_t*)d_ws;                          // 33.5 MB (linear)
    uint8_t* wq = (uint8_t*)d_ws + (size_t)MDIM * KDIM;    // 4.2 MB (packed)

    quant_both_kernel<<<2304, 256, 0, stream>>>(x, xq, weight, wq, s_in, s_w);

    dim3 grid((MDIM / BM) * (NDIM / BN));   // 64 * 16 = 1024
    gemm_fp8_kernel<<<grid, 256, 65536, stream>>>(xq, wq, bias, s_in, s_w, out);
}

// Round 14
// 111.849 us; speedup vs baseline: 2.1329x; 1.0014x over previous
//
#include <hip/hip_runtime.h>
#include <hip/hip_fp16.h>
#include <stdint.h>

// x[16384,2048] f32, w[2048,2048] f32, bias[2048] f32, scalar scales.
// M=16384, N=2048, K=2048. Output f16 values stored as f32.
#define MDIM 16384
#define NDIM 2048
#define KDIM 2048

typedef __attribute__((ext_vector_type(4))) float f32x4;
typedef __attribute__((ext_vector_type(4))) int   i32x4;
typedef __attribute__((ext_vector_type(8))) int   i32x8;

#if defined(__has_builtin)
#if __has_builtin(__builtin_amdgcn_cvt_pk_fp8_f32)
#define HAVE_CVT_PK_FP8 1
#endif
#endif

// ---------------------------------------------------------------------------
// f32 -> e4m3fn (OCP), RTNE, saturating (== clip(+-448) then cast).
// ---------------------------------------------------------------------------
__device__ __forceinline__ unsigned f32_to_e4m3(float x) {
    float q = fminf(448.f, fmaxf(-448.f, x));
    unsigned ub = __float_as_uint(q);
    unsigned sgn = (ub >> 24) & 0x80u;
    float aq = fabsf(q);
    int E = (int)((__float_as_uint(aq) >> 23) & 0xff) - 127;
    if (E < -6) E = -6;
    float rq = __uint_as_float((unsigned)(130 - E) << 23);  // 2^(3-E), exact
    int m = (int)rintf(aq * rq);                            // RTNE, exact scale
    if (m == 16) { m = 8; E += 1; }
    unsigned bits;
    if (m < 8) bits = sgn | (unsigned)m;
    else       bits = sgn | ((unsigned)(E + 7) << 3) | (unsigned)(m - 8);
    return bits;
}

__device__ __forceinline__ uint32_t pack4_e4m3(float a, float b, float c, float d) {
#ifdef HAVE_CVT_PK_FP8
    int r = __builtin_amdgcn_cvt_pk_fp8_f32(a, b, 0, false);   // bytes 0-1
    r = __builtin_amdgcn_cvt_pk_fp8_f32(c, d, r, true);        // bytes 2-3
    return (uint32_t)r;
#else
    return f32_to_e4m3(a) | (f32_to_e4m3(b) << 8) |
           (f32_to_e4m3(c) << 16) | (f32_to_e4m3(d) << 24);
#endif
}

// x-quant: linear layout.  w-quant: fragment-major packed layout Bp
// (verified r8-r13): 2048B block (n16 = col>>4, kb = ktile) holds at
// lane*32 (lane = g*16 + r15) bytes w[n16*16+r15][kb*128 + g*32 .. +31].
__global__ void quant_both_kernel(const float* __restrict__ x,
                                  uint8_t* __restrict__ xq,
                                  const float* __restrict__ w,
                                  uint8_t* __restrict__ wq,
                                  const float* __restrict__ s_in,
                                  const float* __restrict__ s_w) {
    if (blockIdx.x < 2048) {
        float sc = s_in[0];
        unsigned n16 = (unsigned)((size_t)MDIM * KDIM / 16);
        unsigned i = blockIdx.x * 256 + threadIdx.x;
        for (; i < n16; i += 2048 * 256) {
            const float4* xp = (const float4*)(x + (size_t)i * 16);
            uint32_t wd[4];
#pragma unroll
            for (int j = 0; j < 4; ++j) {
                float4 v = xp[j];
                wd[j] = pack4_e4m3(v.x / sc, v.y / sc, v.z / sc, v.w / sc);
            }
            ((uint4*)xq)[i] = make_uint4(wd[0], wd[1], wd[2], wd[3]);
        }
    } else {
        float sc = s_w[0];
        unsigned n16 = (unsigned)((size_t)NDIM * KDIM / 16);
        unsigned i = (blockIdx.x - 2048) * 256 + threadIdx.x;
        for (; i < n16; i += 256 * 256) {
            const float4* xp = (const float4*)(w + (size_t)i * 16);
            uint32_t wd[4];
#pragma unroll
            for (int j = 0; j < 4; ++j) {
                float4 v = xp[j];
                wd[j] = pack4_e4m3(v.x / sc, v.y / sc, v.z / sc, v.w / sc);
            }
            unsigned r = i >> 7, kc = i & 127;
            unsigned idx = ((r >> 4) * 16 + (kc >> 3)) * 128 +
                           ((kc & 7) >> 1) * 32 + (r & 15) * 2 + (kc & 1);
            ((uint4*)wq)[idx] = make_uint4(wd[0], wd[1], wd[2], wd[3]);
        }
    }
}

// ---------------------------------------------------------------------------
// GEMM: C = Aq * Bp^T, fp8 e4m3, mfma_scale_f32_16x16x128_f8f6f4 (unit
// scales: exact, 2x fp8 rate; verified r4-r13).
//
// Round-14: flip the duplicated operand off the LDS port.
//   r13 audit: per-wave 128x64 duplicates af across wc-waves -> LDS port
//   192KB/CU-tile (~2000cy) co-critical with MFMA 2208cy.
//   Now: per-wave 64x128 (af 4 frags LDS, bf 8 frags DIRECT from L2 packed
//   wq). LDS port = (32KB af reads + 16KB DMA) x2 blocks = 96KB/CU-tile
//   ~1000cy << MFMA.  L2 bf = 128KB/CU-tile ~950cy << MFMA.
//   Block 128x256, 4 waves 2Mx2N, 2 blocks/CU (launch_bounds(256,2)).
//   Regs: acc 128 AGPR + bf 64 + af roll 16 + addr ~40 = ~248 (tripwire:
//   FETCH>80MB => spill => revert).
// Per tile t: {STAGE_A(t+1) 4 DMA; fence; af-rolling 4x[ds_read pair +
//   MFMA8]; LOAD_BF_ALL(t+1) 16 loads; vmcnt(16) [FIFO: drains the 4 DMA,
//   leaves bf(t+1) in flight across the barrier]; barrier}.
//   Entry invariant: bf(t) 16 in flight (compiler inserts vmcnt(4) before
//   first MFMA), A(t) landed.
// A chunk swizzle per 128B row: phys=(c+row)&7, linear gload_lds dest,
// inverse on global src, same perm on af reads (2-way residual, r4-r13).
// Epilogue: [32][256] f32 slab (32KB = the dbuf), 4 passes, 1KiB rows.
// ---------------------------------------------------------------------------
#define BM 128
#define BN 256
#define BKB 128
#define NKT (KDIM / BKB)   // 16

__device__ __forceinline__ void gload_lds16(const uint8_t* g, uint8_t* l) {
    __builtin_amdgcn_global_load_lds(
        (const __attribute__((address_space(1))) void*)g,
        (__attribute__((address_space(3))) void*)l, 16, 0, 0);
}

__device__ __forceinline__ void barrier_raw() {
    asm volatile("" ::: "memory");
    __builtin_amdgcn_s_barrier();
    asm volatile("" ::: "memory");
}

__global__ __launch_bounds__(256, 2) void gemm_fp8_kernel(
    const uint8_t* __restrict__ Aq, const uint8_t* __restrict__ Bp,
    const float* __restrict__ bias, const float* __restrict__ s_in,
    const float* __restrict__ s_w, float* __restrict__ out) {

    extern __shared__ uint8_t lds[];   // 32768 B: 2 x 16KiB A-dbuf / slab

    // XCD-aware bijective swizzle (nwg = 1024, divisible by 8)
    int nwg = gridDim.x;
    int cpx = nwg >> 3;
    int bid = blockIdx.x;
    int swz = (bid & 7) * cpx + (bid >> 3);
    int tm = swz >> 3;                 // tiles_n = 8
    int tn = swz & 7;
    int row0 = tm * BM;
    int col0 = tn * BN;

    int tid  = threadIdx.x;
    int lane = tid & 63;
    int wid  = tid >> 6;               // 4 waves
    int wr = wid >> 1, wc = wid & 1;   // 2M x 2N, per-wave 64x128
    int r15 = lane & 15;
    int g   = lane >> 4;

    int perm0 = ((2 * g + r15) & 7) << 4;
    int perm1 = ((2 * g + 1 + r15) & 7) << 4;

    // ---- A staging: 1024 chunks/tile (128 rows x 8), 4 per thread ----
    int ssrc[4], sdst[4];
#pragma unroll
    for (int i = 0; i < 4; ++i) {
        int p = i * 256 + tid;
        int lrow = p >> 3;
        int c = ((p & 7) - (lrow & 7)) & 7;
        ssrc[i] = lrow * KDIM + c * 16;
        sdst[i] = p * 16;
    }
    const uint8_t* Asrc = Aq + (size_t)row0 * KDIM;

#define STAGE_A(KT, BUF)                                                      \
    {                                                                         \
        _Pragma("unroll")                                                     \
        for (int j_ = 0; j_ < 4; ++j_)                                        \
            gload_lds16(Asrc + ssrc[j_] + (size_t)(KT) * BKB, (BUF) + sdst[j_]); \
    }

    // ---- B fragment base (packed layout; r8-r13-verified) ----
    // frag n (n=0..7) of K-tile kt at: Bbase + n*32768 + kt*2048
    const uint8_t* Bbase = Bp + (size_t)(tn * 16 + wc * 8) * 32768 + lane * 32;

#define LOAD_BF1(DST, N, KT)                                                  \
    {                                                                         \
        const uint8_t* p_ = Bbase + (size_t)(N) * 32768 + (size_t)(KT) * 2048; \
        i32x4 lo = *(const i32x4*)p_;                                         \
        i32x4 hi = *(const i32x4*)(p_ + 16);                                  \
        _Pragma("unroll")                                                     \
        for (int q_ = 0; q_ < 4; ++q_) { DST[q_] = lo[q_]; DST[4 + q_] = hi[q_]; } \
    }

#define LOAD_BF_ALL(KT)                                                       \
    LOAD_BF1(bf0, 0, KT); LOAD_BF1(bf1, 1, KT);                               \
    LOAD_BF1(bf2, 2, KT); LOAD_BF1(bf3, 3, KT);                               \
    LOAD_BF1(bf4, 4, KT); LOAD_BF1(bf5, 5, KT);                               \
    LOAD_BF1(bf6, 6, KT); LOAD_BF1(bf7, 7, KT);

    int aRow0 = wr * 64 + r15;         // + m*16

#define LOAD_AF1(DST, bo, M)                                                  \
    {                                                                         \
        const uint8_t* rp = lds + (bo) + (aRow0 + (M) * 16) * 128;            \
        i32x4 lo = *(const i32x4*)(rp + perm0);                               \
        i32x4 hi = *(const i32x4*)(rp + perm1);                               \
        _Pragma("unroll")                                                     \
        for (int q_ = 0; q_ < 4; ++q_) { DST[q_] = lo[q_]; DST[4 + q_] = hi[q_]; } \
    }

#define MFMA8(AF, M)                                                          \
    __builtin_amdgcn_s_setprio(1);                                            \
    acc[M][0] = __builtin_amdgcn_mfma_scale_f32_16x16x128_f8f6f4(             \
        AF, bf0, acc[M][0], 0, 0, 0, 127, 0, 127);                            \
    acc[M][1] = __builtin_amdgcn_mfma_scale_f32_16x16x128_f8f6f4(             \
        AF, bf1, acc[M][1], 0, 0, 0, 127, 0, 127);                            \
    acc[M][2] = __builtin_amdgcn_mfma_scale_f32_16x16x128_f8f6f4(             \
        AF, bf2, acc[M][2], 0, 0, 0, 127, 0, 127);                            \
    acc[M][3] = __builtin_amdgcn_mfma_scale_f32_16x16x128_f8f6f4(             \
        AF, bf3, acc[M][3], 0, 0, 0, 127, 0, 127);                            \
    acc[M][4] = __builtin_amdgcn_mfma_scale_f32_16x16x128_f8f6f4(             \
        AF, bf4, acc[M][4], 0, 0, 0, 127, 0, 127);                            \
    acc[M][5] = __builtin_amdgcn_mfma_scale_f32_16x16x128_f8f6f4(             \
        AF, bf5, acc[M][5], 0, 0, 0, 127, 0, 127);                            \
    acc[M][6] = __builtin_amdgcn_mfma_scale_f32_16x16x128_f8f6f4(             \
        AF, bf6, acc[M][6], 0, 0, 0, 127, 0, 127);                            \
    acc[M][7] = __builtin_amdgcn_mfma_scale_f32_16x16x128_f8f6f4(             \
        AF, bf7, acc[M][7], 0, 0, 0, 127, 0, 127);                            \
    __builtin_amdgcn_s_setprio(0);

    f32x4 acc[4][8];
#pragma unroll
    for (int m = 0; m < 4; ++m)
#pragma unroll
        for (int n = 0; n < 8; ++n)
            acc[m][n] = (f32x4){0.f, 0.f, 0.f, 0.f};

    i32x8 bf0, bf1, bf2, bf3, bf4, bf5, bf6, bf7;

    uint8_t* buf0 = &lds[0];
    uint8_t* buf1 = &lds[16384];

    // ---- prologue: stage A(0) [4 DMA]; bf(0) [16 loads];
    //      vmcnt(16) drains DMA, leaves bf(0) in flight; barrier ----
    STAGE_A(0, buf0);
    asm volatile("" ::: "memory");     // pin DMA before bf in VMEM FIFO
    LOAD_BF_ALL(0);
    asm volatile("s_waitcnt vmcnt(16)" ::: "memory");
    barrier_raw();

    // Entry invariant tile T: bf(T) 16 in flight (oldest), A(T) landed.
#define TILE_BODY(T)                                                          \
    {                                                                         \
        const unsigned bo = ((unsigned)(T) & 1) << 14;                        \
        uint8_t* nxt_ = (((T) & 1) ? buf0 : buf1);                            \
        if ((T) + 1 < NKT) STAGE_A((T) + 1, nxt_);   /* 4 DMA after bf(T) */  \
        asm volatile("" ::: "memory");                                        \
        i32x8 afE, afO;                                                       \
        LOAD_AF1(afE, bo, 0);   /* compiler: counted vmcnt for bf(T) */       \
        LOAD_AF1(afO, bo, 1); MFMA8(afE, 0);                                  \
        LOAD_AF1(afE, bo, 2); MFMA8(afO, 1);                                  \
        LOAD_AF1(afO, bo, 3); MFMA8(afE, 2);                                  \
                              MFMA8(afO, 3);                                  \
        if ((T) + 1 < NKT) {                                                  \
            LOAD_BF_ALL((T) + 1);          /* 16 loads, reuse bf regs */      \
            asm volatile("s_waitcnt vmcnt(16)" ::: "memory"); /* A(T+1) in */ \
        } else {                                                              \
            asm volatile("s_waitcnt vmcnt(0)" ::: "memory");                  \
        }                                                                     \
        barrier_raw();                                                        \
    }

    for (int t = 0; t < NKT; ++t)
        TILE_BODY(t);

    // ---- epilogue: f16 double-round + bias; [32][256] f32 slab, 4 passes --
    float s = s_in[0] * s_w[0];
    float* slab = (float*)lds;
    __half hb[8];
#pragma unroll
    for (int n = 0; n < 8; ++n)
        hb[n] = __float2half(bias[col0 + wc * 128 + n * 16 + r15]);

#pragma unroll
    for (int q = 0; q < 4; ++q) {            // out rows [q*32, q*32+32)
        if (wr == (q >> 1)) {
            const int mbase = 2 * (q & 1);
#pragma unroll
            for (int n = 0; n < 8; ++n) {
                int colb = wc * 128 + n * 16 + r15;
#pragma unroll
                for (int mm = 0; mm < 2; ++mm) {
                    int sr = mm * 16 + g * 4;
#pragma unroll
                    for (int r = 0; r < 4; ++r) {
                        __half h = __float2half(acc[mbase + mm][n][r] * s);
                        slab[(sr + r) * 256 + colb] = __half2float(__hadd(h, hb[n]));
                    }
                }
            }
        }
        barrier_raw();
        // 32 rows x 1KiB; each wave 8 rows (64 lanes x 16B per row)
#pragma unroll
        for (int it = 0; it < 8; ++it) {
            int srow = wid * 8 + it;
            f32x4 vv = *(const f32x4*)&slab[srow * 256 + lane * 4];
            int grow = row0 + q * 32 + srow;
            *(f32x4*)&out[(size_t)grow * NDIM + col0 + lane * 4] = vv;
        }
        barrier_raw();
    }
#undef STAGE_A
#undef LOAD_BF1
#undef LOAD_BF_ALL
#undef LOAD_AF1
#undef MFMA8
#undef TILE_BODY
}

// ---------------------------------------------------------------------------
extern "C" void kernel_launch(void* const* d_in, const int* in_sizes, int n_in,
                              void* d_out, int out_size, void* d_ws, size_t ws_size,
                              hipStream_t stream) {
    const float* x      = (const float*)d_in[0];   // [16384, 2048]
    const float* weight = (const float*)d_in[1];   // [2048, 2048]
    const float* bias   = (const float*)d_in[2];   // [2048]
    const float* s_in   = (const float*)d_in[3];   // [1]
    const float* s_w    = (const float*)d_in[4];   // [1]
    float* out          = (float*)d_out;

    uint8_t* xq = (uint8_t*)d_ws;                          // 33.5 MB (linear)
    uint8_t* wq = (uint8_t*)d_ws + (size_t)MDIM * KDIM;    // 4.2 MB (packed)

    quant_both_kernel<<<2304, 256, 0, stream>>>(x, xq, weight, wq, s_in, s_w);

    dim3 grid((MDIM / BM) * (NDIM / BN));   // 128 * 8 = 1024
    gemm_fp8_kernel<<<grid, 256, 32768, stream>>>(xq, wq, bias, s_in, s_w, out);
}